// Round 1
// 9331.650 us; speedup vs baseline: 1.1555x; 1.1555x over previous
//
#include <hip/hip_runtime.h>
#include <hip/hip_bf16.h>
#include <cmath>

#define BN_SCALE_F 0.9999950000374997f

typedef __attribute__((ext_vector_type(8))) short short8;
typedef __attribute__((ext_vector_type(4))) float floatx4;

static __device__ __forceinline__ ushort f2bf(float x) {
    union { float f; unsigned u; } c; c.f = x;
    unsigned r = (c.u + 0x7FFFu + ((c.u >> 16) & 1u)) >> 16;
    return (ushort)r;
}
static __device__ __forceinline__ float bf2f(ushort h) {
    union { unsigned u; float f; } c; c.u = ((unsigned)h) << 16;
    return c.f;
}

// ---------------------------------------------------------------------------
// Weight repack: OIDHW fp32 [CO][CI][27] -> [CO][27][CI] bf16 hi/lo planes
// ---------------------------------------------------------------------------
__global__ __launch_bounds__(256) void repack_kernel(
    const float* __restrict__ w, ushort* __restrict__ oh, ushort* __restrict__ ol,
    int CI, int total)
{
    int idx = blockIdx.x * 256 + threadIdx.x;
    if (idx >= total) return;
    int ci = idx % CI;
    int t  = (idx / CI) % 27;
    int co = idx / (CI * 27);
    float v = w[((size_t)co * CI + ci) * 27 + t];
    ushort h = f2bf(v);
    oh[idx] = h;
    ol[idx] = f2bf(v - bf2f(h));
}

// ---------------------------------------------------------------------------
// conv1: fp32 compute (Cin=3), BN+ReLU+pool(1,2,2), writes NDHWC bf16 hi/lo.
// ---------------------------------------------------------------------------
__global__ __launch_bounds__(256) void conv1_ndhwc(
    const float* __restrict__ sup, const float* __restrict__ qry, int clipBase,
    const float* __restrict__ wgt, const float* __restrict__ bias,
    ushort* __restrict__ outH, ushort* __restrict__ outL)
{
    __shared__ float sIn[4][10][12];
    __shared__ float sW[16][28];
    const int tid = threadIdx.x;
    const int bw = blockIdx.x % 14;
    const int bh = (blockIdx.x / 14) % 14;
    const int bd = blockIdx.x / 196;
    const int coL = tid >> 4;
    const int co  = blockIdx.y * 16 + coL;
    const int sp  = tid & 15;
    const int sh = sp >> 2, sw = sp & 3;
    const int n = blockIdx.z;
    const int clip = clipBase + n;
    const float* src = (clip < 12) ? (sup + (size_t)clip * 602112)
                                   : (qry + (size_t)(clip - 12) * 602112);
    const int d0 = 2 * bd, h0 = 8 * bh, w0 = 8 * bw;

    float acc[8] = {0.f,0.f,0.f,0.f,0.f,0.f,0.f,0.f};
    for (int ci = 0; ci < 3; ci++) {
        for (int t = tid; t < 832; t += 256) {
            if (t < 400) {
                int pd = t / 100; int rem = t - pd * 100;
                int ph = rem / 10; int pw = rem - ph * 10;
                int gd = d0 - 1 + pd, gh = h0 - 1 + ph, gw = w0 - 1 + pw;
                float v = 0.f;
                if ((unsigned)gd < 16u && (unsigned)gh < 112u && (unsigned)gw < 112u)
                    v = src[(size_t)gd * 37632 + ci * 12544 + gh * 112 + gw];
                sIn[pd][ph][pw] = v;
            } else {
                int t2 = t - 400;
                if (t2 < 432) {
                    int cl = t2 / 27, k = t2 - cl * 27;
                    sW[cl][k] = wgt[((size_t)(blockIdx.y * 16 + cl) * 3 + ci) * 27 + k];
                }
            }
        }
        __syncthreads();
        float wr[27];
#pragma unroll
        for (int k = 0; k < 27; k++) wr[k] = sW[coL][k];
#pragma unroll
        for (int dd = 0; dd < 4; dd++) {
            float qv[16];
#pragma unroll
            for (int hh = 0; hh < 4; hh++)
#pragma unroll
                for (int ww = 0; ww < 4; ww++)
                    qv[hh * 4 + ww] = sIn[dd][2 * sh + hh][2 * sw + ww];
#pragma unroll
            for (int kd = 0; kd < 3; kd++) {
                int deltad = dd - kd;
                if (deltad < 0 || deltad > 1) continue;
#pragma unroll
                for (int kh = 0; kh < 3; kh++)
#pragma unroll
                    for (int kw = 0; kw < 3; kw++) {
                        float wv = wr[kd * 9 + kh * 3 + kw];
#pragma unroll
                        for (int dh = 0; dh < 2; dh++)
#pragma unroll
                            for (int dw = 0; dw < 2; dw++)
                                acc[deltad * 4 + dh * 2 + dw] =
                                    fmaf(wv, qv[(dh + kh) * 4 + (dw + kw)],
                                         acc[deltad * 4 + dh * 2 + dw]);
                    }
            }
        }
        __syncthreads();
    }
    const float b = __ldg(bias + co);
    const int oh = 4 * bh + sh, ow = 4 * bw + sw;
#pragma unroll
    for (int dd = 0; dd < 2; dd++) {
        float m = 0.f;
#pragma unroll
        for (int k = 0; k < 4; k++) m = fmaxf(m, (acc[dd * 4 + k] + b) * BN_SCALE_F);
        size_t idx = ((((size_t)n * 16 + (d0 + dd)) * 56 + oh) * 56 + ow) * 64 + co;
        ushort h = f2bf(m);
        outH[idx] = h;
        outL[idx] = f2bf(m - bf2f(h));
    }
}

// ---------------------------------------------------------------------------
// MFMA implicit-GEMM 3x3x3 conv, bf16 hi/lo split (3-product), NDHWC.
// Block: 64co x 256sp (spatial box 4x8x8); wave: 64co x 64sp.
// LDS chunk placement XOR-swizzled: 16B chunk g of row `pos` lives at slot
// g ^ ((pos>>1)&3)  -> bank slots (4*pos + g^((pos>>1)&3)) mod 8 cover all 8
// slots over any 8 consecutive pos => 2-way (free) instead of 8-way conflicts.
// MODE 0: 'a' conv+ReLU -> NDHWC hi/lo
// MODE 1: 'b' conv+BN+ReLU+pool2 -> NDHWC hi/lo
// MODE 2: 'b' conv+BN+ReLU+pool2 -> NCDHW fp32
// MODE 3: 'b' conv+BN+ReLU+pool2 pad(0,1,1) (D=2,H=W=7 -> 1x4x4) -> NCDHW fp32
// ---------------------------------------------------------------------------
template<int CIN,int COUT,int D,int H,int W,int MODE>
__global__ __launch_bounds__(256,1) void conv_mfma(
    const ushort* __restrict__ inH, const ushort* __restrict__ inL,
    const ushort* __restrict__ wH,  const ushort* __restrict__ wL,
    const float* __restrict__ bias,
    ushort* __restrict__ outH, ushort* __restrict__ outL, float* __restrict__ outF)
{
    constexpr int TW = (W + 7) / 8;
    constexpr int TH = (H + 7) / 8;
    __shared__ ushort sMem[19200 * 2 + 6144 * 2];
    ushort* sPH = sMem;
    ushort* sPL = sMem + 19200;
    ushort* sWH = sMem + 38400;
    ushort* sWL = sMem + 44544;

    const int tid = threadIdx.x;
    const int lane = tid & 63;
    const int wv = tid >> 6;
    const int n15 = lane & 15;
    const int g4 = lane >> 4;
    const int tw = blockIdx.x % TW;
    const int th = (blockIdx.x / TW) % TH;
    const int td = blockIdx.x / (TW * TH);
    const int coG0 = blockIdx.y * 64;
    const int n = blockIdx.z;

    int sdv[4], shv[4], swv[4];
#pragma unroll
    for (int spg = 0; spg < 4; spg++) {
        int s = wv * 64 + spg * 16 + n15;
        sdv[spg] = s >> 6; shv[spg] = (s >> 3) & 7; swv[spg] = s & 7;
    }

    const size_t inBase = (size_t)n * CIN * D * H * W;

    floatx4 acc[4][4];
#pragma unroll
    for (int i = 0; i < 4; i++)
#pragma unroll
        for (int j = 0; j < 4; j++) acc[i][j] = (floatx4){0.f, 0.f, 0.f, 0.f};

    uint4 pfH[3], pfL[3];

    for (int c0 = 0; c0 < CIN; c0 += 32) {
        // stage input patch (6x10x10 x 32ci), hi & lo  (swizzled chunk slots)
        for (int t = tid; t < 2400; t += 256) {
            int pos = t >> 2, g = t & 3;
            int pd = pos / 100; int rem = pos - pd * 100;
            int ph = rem / 10;  int pw = rem - ph * 10;
            int gd = td * 4 - 1 + pd;
            int gh = th * 8 - 1 + ph;
            int gw = tw * 8 - 1 + pw;
            uint4 vh = {0u,0u,0u,0u}, vl = {0u,0u,0u,0u};
            if ((unsigned)gd < (unsigned)D && (unsigned)gh < (unsigned)H && (unsigned)gw < (unsigned)W) {
                size_t gi = inBase + (((size_t)gd * H + gh) * W + gw) * CIN + c0 + g * 8;
                vh = *(const uint4*)(inH + gi);
                vl = *(const uint4*)(inL + gi);
            }
            int sg = g ^ ((pos >> 1) & 3);
            *(uint4*)(sPH + pos * 32 + sg * 8) = vh;
            *(uint4*)(sPL + pos * 32 + sg * 8) = vl;
        }
        if (c0 == 0) {
#pragma unroll
            for (int k = 0; k < 3; k++) {
                int t = tid + k * 256;
                int kw = t >> 8, col = (t >> 2) & 63, g8 = t & 3;
                size_t src = ((size_t)(coG0 + col) * 27 + kw) * CIN + g8 * 8;
                pfH[k] = *(const uint4*)(wH + src);
                pfL[k] = *(const uint4*)(wL + src);
            }
        }
        __syncthreads();

        for (int row = 0; row < 9; row++) {
            // commit prefetched weight row (3 taps x 64co x 32ci), swizzled
#pragma unroll
            for (int k = 0; k < 3; k++) {
                int t = tid + k * 256;
                int kw = t >> 8, col = (t >> 2) & 63, g8 = t & 3;
                int wpos = kw * 64 + col;
                int dst = wpos * 32 + (g8 ^ ((wpos >> 1) & 3)) * 8;
                *(uint4*)(sWH + dst) = pfH[k];
                *(uint4*)(sWL + dst) = pfL[k];
            }
            __syncthreads();
            // prefetch next row (or row0 of next chunk)
            {
                int nc0 = c0, nrow = row + 1;
                if (nrow == 9) { nrow = 0; nc0 = c0 + 32; }
                if (nc0 < CIN) {
#pragma unroll
                    for (int k = 0; k < 3; k++) {
                        int t = tid + k * 256;
                        int kw = t >> 8, col = (t >> 2) & 63, g8 = t & 3;
                        size_t src = ((size_t)(coG0 + col) * 27 + nrow * 3 + kw) * CIN + nc0 + g8 * 8;
                        pfH[k] = *(const uint4*)(wH + src);
                        pfL[k] = *(const uint4*)(wL + src);
                    }
                }
            }
            const int kd = row / 3, kh = row - kd * 3;
            int pbase[4];
#pragma unroll
            for (int spg = 0; spg < 4; spg++)
                pbase[spg] = ((sdv[spg] + kd) * 10 + shv[spg] + kh) * 10 + swv[spg];
#pragma unroll
            for (int kw = 0; kw < 3; kw++) {
                short8 Bh[4], Bl[4];
#pragma unroll
                for (int spg = 0; spg < 4; spg++) {
                    int p = pbase[spg] + kw;
                    int off = p * 32 + (g4 ^ ((p >> 1) & 3)) * 8;
                    Bh[spg] = *(const short8*)(sPH + off);
                    Bl[spg] = *(const short8*)(sPL + off);
                }
#pragma unroll
                for (int cog = 0; cog < 4; cog++) {
                    int pa = kw * 64 + cog * 16 + n15;
                    int offA = pa * 32 + (g4 ^ ((pa >> 1) & 3)) * 8;
                    short8 Ah = *(const short8*)(sWH + offA);
                    short8 Al = *(const short8*)(sWL + offA);
#pragma unroll
                    for (int spg = 0; spg < 4; spg++) {
                        acc[cog][spg] = __builtin_amdgcn_mfma_f32_16x16x32_bf16(Ah, Bh[spg], acc[cog][spg], 0, 0, 0);
                        acc[cog][spg] = __builtin_amdgcn_mfma_f32_16x16x32_bf16(Ah, Bl[spg], acc[cog][spg], 0, 0, 0);
                        acc[cog][spg] = __builtin_amdgcn_mfma_f32_16x16x32_bf16(Al, Bh[spg], acc[cog][spg], 0, 0, 0);
                    }
                }
            }
            __syncthreads();
        }
    }

    // epilogue: acc -> LDS (padded) -> pooled/plain stores
    float* sEp = (float*)sMem;
#pragma unroll
    for (int cog = 0; cog < 4; cog++)
#pragma unroll
        for (int spg = 0; spg < 4; spg++) {
            int sp = wv * 64 + spg * 16 + n15;
#pragma unroll
            for (int r = 0; r < 4; r++) {
                int co = cog * 16 + g4 * 4 + r;
                sEp[sp * 65 + co] = acc[cog][spg][r];
            }
        }
    __syncthreads();

    const int co = tid & 63;
    const int coG = coG0 + co;
    const float b = __ldg(bias + coG);

    if constexpr (MODE == 0) {
#pragma unroll 4
        for (int i = 0; i < 64; i++) {
            int sp = i * 4 + (tid >> 6);
            int ld = sp >> 6, lh = (sp >> 3) & 7, lw = sp & 7;
            int gd = td * 4 + ld, gh = th * 8 + lh, gw = tw * 8 + lw;
            if (gd < D && gh < H && gw < W) {
                float y = fmaxf(sEp[sp * 65 + co] + b, 0.f);
                size_t idx = ((((size_t)n * D + gd) * H + gh) * W + gw) * COUT + coG;
                ushort h = f2bf(y);
                outH[idx] = h;
                outL[idx] = f2bf(y - bf2f(h));
            }
        }
    } else if constexpr (MODE == 3) {
        // pool k2s2 pad(0,1,1) over (2,7,7) -> (1,4,4), NCDHW fp32
#pragma unroll
        for (int i = 0; i < 4; i++) {
            int pp = i * 4 + (tid >> 6);      // 0..15
            int oh = pp >> 2, ow = pp & 3;
            float m = -1e30f;
#pragma unroll
            for (int dd = 0; dd < 2; dd++)
#pragma unroll
                for (int dh = 0; dh < 2; dh++) {
                    int h = 2 * oh - 1 + dh; if (h < 0 || h >= 7) continue;
#pragma unroll
                    for (int dw = 0; dw < 2; dw++) {
                        int w = 2 * ow - 1 + dw; if (w < 0 || w >= 7) continue;
                        int sp = dd * 64 + h * 8 + w;
                        m = fmaxf(m, sEp[sp * 65 + co]);
                    }
                }
            float y = fmaxf((m + b) * BN_SCALE_F, 0.f);
            outF[(size_t)n * 8192 + (size_t)coG * 16 + oh * 4 + ow] = y;
        }
    } else {
        constexpr int OD = D / 2, OH = H / 2, OW = W / 2;
#pragma unroll
        for (int i = 0; i < 8; i++) {
            int pp = i * 4 + (tid >> 6);
            int ppd = pp >> 4, pph = (pp >> 2) & 3, ppw = pp & 3;
            int gpd = td * 2 + ppd, gph = th * 4 + pph, gpw = tw * 4 + ppw;
            if (gph < OH && gpw < OW) {
                float m = -1e30f;
#pragma unroll
                for (int dd = 0; dd < 2; dd++)
#pragma unroll
                    for (int dh = 0; dh < 2; dh++)
#pragma unroll
                        for (int dw = 0; dw < 2; dw++) {
                            int sp = (ppd * 2 + dd) * 64 + (pph * 2 + dh) * 8 + (ppw * 2 + dw);
                            m = fmaxf(m, sEp[sp * 65 + co]);
                        }
                float y = fmaxf((m + b) * BN_SCALE_F, 0.f);
                if constexpr (MODE == 1) {
                    size_t idx = ((((size_t)n * OD + gpd) * OH + gph) * OW + gpw) * COUT + coG;
                    ushort h = f2bf(y);
                    outH[idx] = h;
                    outL[idx] = f2bf(y - bf2f(h));
                } else {
                    size_t idx = ((((size_t)n * COUT + coG) * OD + gpd) * OH + gph) * OW + gpw;
                    outF[idx] = y;
                }
            }
        }
    }
}

// ---------------------------------------------------------------------------
// FC: one warp per output channel, accumulate all 24 samples so the weight
// matrix streams from HBM exactly once (x stays L2-resident: 24*8192*4=786KB).
// ---------------------------------------------------------------------------
__global__ __launch_bounds__(256) void fc_kernel(
    const float* __restrict__ x, const float* __restrict__ wgt,
    const float* __restrict__ bias, float* __restrict__ out,
    int K, int Cout)
{
    int co = (blockIdx.x * 256 + threadIdx.x) >> 6;
    int lane = threadIdx.x & 63;
    if (co >= Cout) return;
    const float4* wp = (const float4*)(wgt + (size_t)co * K);
    int K4 = K >> 2;
    float s[24];
#pragma unroll
    for (int n = 0; n < 24; n++) s[n] = 0.f;
    for (int k = lane; k < K4; k += 64) {
        float4 b = __ldg(wp + k);
#pragma unroll
        for (int n = 0; n < 24; n++) {
            float4 a = __ldg((const float4*)(x + (size_t)n * K) + k);
            s[n] += a.x * b.x + a.y * b.y + a.z * b.z + a.w * b.w;
        }
    }
    const float bb = __ldg(bias + co);
#pragma unroll
    for (int n = 0; n < 24; n++) {
        float v = s[n];
#pragma unroll
        for (int off = 32; off > 0; off >>= 1) v += __shfl_down(v, off, 64);
        if (lane == 0)
            out[(size_t)n * Cout + co] = fmaxf((v + bb) * BN_SCALE_F, 0.f);
    }
}

__global__ __launch_bounds__(256) void dots_kernel(
    const float* __restrict__ feat, float* __restrict__ dots)
{
    int task = blockIdx.x; int tid = threadIdx.x;
    int ra, rb;
    if (task < 24) { ra = task; rb = task; }
    else {
        int t = task - 24;
        int q = t / 48; int r = t % 48;
        int i = r / 12; int s = (r % 12) / 4; int j = r % 4;
        ra = 12 + q * 4 + i;
        rb = s * 4 + j;
    }
    const float4* A = (const float4*)(feat + (size_t)ra * 4096);
    const float4* B = (const float4*)(feat + (size_t)rb * 4096);
    float acc = 0.f;
    for (int k = tid; k < 1024; k += 256) {
        float4 a = A[k], b = B[k];
        acc += a.x * b.x + a.y * b.y + a.z * b.z + a.w * b.w;
    }
#pragma unroll
    for (int off = 32; off > 0; off >>= 1) acc += __shfl_down(acc, off, 64);
    __shared__ float red[4];
    if ((tid & 63) == 0) red[tid >> 6] = acc;
    __syncthreads();
    if (tid == 0) dots[task] = red[0] + red[1] + red[2] + red[3];
}

__global__ __launch_bounds__(64) void sinkhorn_kernel(
    const float* __restrict__ dots, float* __restrict__ out)
{
    int t = threadIdx.x;
    if (t >= 9) return;
    int q = t / 3, s = t % 3;
    float Km[16], sem[16];
#pragma unroll
    for (int i = 0; i < 4; i++) {
        float nq = sqrtf(dots[12 + q * 4 + i]) + 1e-8f;
#pragma unroll
        for (int j = 0; j < 4; j++) {
            float ns = sqrtf(dots[s * 4 + j]) + 1e-8f;
            float d = dots[24 + q * 48 + i * 12 + s * 4 + j];
            float c = 1.0f - d / (nq * ns);
            float ti = i * 0.25f, tj = j * 0.25f;
            float d2 = (ti - tj) * (ti - tj);
            float pc = expf(-1.0f / (d2 + 1.0f));
            sem[i * 4 + j] = c;
            Km[i * 4 + j] = expf(-7.0f * (c + 0.4f * pc));
        }
    }
    float u[4] = {0.25f, 0.25f, 0.25f, 0.25f}, v[4];
    for (int it = 0; it < 100; it++) {
#pragma unroll
        for (int j = 0; j < 4; j++) {
            float sj = Km[j] * u[0] + Km[4 + j] * u[1] + Km[8 + j] * u[2] + Km[12 + j] * u[3];
            v[j] = 0.25f / (sj + 1e-9f);
        }
#pragma unroll
        for (int i = 0; i < 4; i++) {
            float si = Km[i * 4] * v[0] + Km[i * 4 + 1] * v[1] + Km[i * 4 + 2] * v[2] + Km[i * 4 + 3] * v[3];
            u[i] = 0.25f / (si + 1e-9f);
        }
    }
#pragma unroll
    for (int j = 0; j < 4; j++) {
        float sj = Km[j] * u[0] + Km[4 + j] * u[1] + Km[8 + j] * u[2] + Km[12 + j] * u[3];
        v[j] = 0.25f / (sj + 1e-9f);
    }
    float tc = 0.f;
#pragma unroll
    for (int i = 0; i < 4; i++)
#pragma unroll
        for (int j = 0; j < 4; j++)
            tc += u[i] * Km[i * 4 + j] * v[j] * sem[i * 4 + j];
    out[q * 3 + s] = -tc;
}

// ---------------------------------------------------------------------------
extern "C" void kernel_launch(void* const* d_in, const int* in_sizes, int n_in,
                              void* d_out, int out_size, void* d_ws, size_t ws_size,
                              hipStream_t stream)
{
    const float* sup = (const float*)d_in[0];
    const float* qry = (const float*)d_in[1];
    const float* w1  = (const float*)d_in[2];  const float* b1  = (const float*)d_in[3];
    const float* w2  = (const float*)d_in[4];  const float* b2  = (const float*)d_in[5];
    const float* w3a = (const float*)d_in[6];  const float* b3a = (const float*)d_in[7];
    const float* w3b = (const float*)d_in[8];  const float* b3b = (const float*)d_in[9];
    const float* w4a = (const float*)d_in[10]; const float* b4a = (const float*)d_in[11];
    const float* w4b = (const float*)d_in[12]; const float* b4b = (const float*)d_in[13];
    const float* w5a = (const float*)d_in[14]; const float* b5a = (const float*)d_in[15];
    const float* w5b = (const float*)d_in[16]; const float* b5b = (const float*)d_in[17];
    const float* w6  = (const float*)d_in[18]; const float* b6  = (const float*)d_in[19];
    const float* w7  = (const float*)d_in[20]; const float* b7  = (const float*)d_in[21];
    float* out = (float*)d_out;

    char* wsB = (char*)d_ws;
    size_t off = 0;
    auto carve = [&](size_t bytes) -> char* {
        char* p = wsB + off;
        off = (off + bytes + 255) & ~(size_t)255;
        return p;
    };

    // repacked weights (bf16 hi/lo), [CO][27][CI]
    const int RW2 = 128 * 27 * 64, RW3a = 256 * 27 * 128, RW3b = 256 * 27 * 256;
    const int RW4a = 512 * 27 * 256, RW4b = 512 * 27 * 512, RW5 = 512 * 27 * 512;
    ushort* w2H  = (ushort*)carve((size_t)RW2 * 2);  ushort* w2L  = (ushort*)carve((size_t)RW2 * 2);
    ushort* w3aH = (ushort*)carve((size_t)RW3a * 2); ushort* w3aL = (ushort*)carve((size_t)RW3a * 2);
    ushort* w3bH = (ushort*)carve((size_t)RW3b * 2); ushort* w3bL = (ushort*)carve((size_t)RW3b * 2);
    ushort* w4aH = (ushort*)carve((size_t)RW4a * 2); ushort* w4aL = (ushort*)carve((size_t)RW4a * 2);
    ushort* w4bH = (ushort*)carve((size_t)RW4b * 2); ushort* w4bL = (ushort*)carve((size_t)RW4b * 2);
    ushort* w5aH = (ushort*)carve((size_t)RW5 * 2);  ushort* w5aL = (ushort*)carve((size_t)RW5 * 2);
    ushort* w5bH = (ushort*)carve((size_t)RW5 * 2);  ushort* w5bL = (ushort*)carve((size_t)RW5 * 2);

    // persistent tail buffers (24 clips)
    ushort* c4H = (ushort*)carve((size_t)24 * 50176 * 2);
    ushort* c4L = (ushort*)carve((size_t)24 * 50176 * 2);
    ushort* c5H = (ushort*)carve((size_t)24 * 50176 * 2);
    ushort* c5L = (ushort*)carve((size_t)24 * 50176 * 2);
    float* x5b24 = (float*)carve((size_t)24 * 8192 * 4);
    float* fc6o  = (float*)carve((size_t)24 * 4096 * 4);
    float* feat  = (float*)carve((size_t)24 * 4096 * 4);
    float* dotsb = (float*)carve(256 * 4);

    const size_t fixed = off;
    const long long P1 = 3211264LL, P2 = 802816LL;      // elems per clip (regions A/B)
    const long long perG = (P1 + P2) * 2 * 2;           // bytes/clip: hi+lo planes
    int G = 1;
    const int cands[8] = {24, 12, 8, 6, 4, 3, 2, 1};
    for (int k = 0; k < 8; k++) {
        if (fixed + (size_t)(perG * cands[k]) + 4096 <= ws_size) { G = cands[k]; break; }
    }
    ushort* AH = (ushort*)carve((size_t)G * P1 * 2);
    ushort* AL = (ushort*)carve((size_t)G * P1 * 2);
    ushort* BH = (ushort*)carve((size_t)G * P2 * 2);
    ushort* BL = (ushort*)carve((size_t)G * P2 * 2);

    // --- weight repack (once per call) ---
    repack_kernel<<<(RW2  + 255) / 256, 256, 0, stream>>>(w2,  w2H,  w2L,  64,  RW2);
    repack_kernel<<<(RW3a + 255) / 256, 256, 0, stream>>>(w3a, w3aH, w3aL, 128, RW3a);
    repack_kernel<<<(RW3b + 255) / 256, 256, 0, stream>>>(w3b, w3bH, w3bL, 256, RW3b);
    repack_kernel<<<(RW4a + 255) / 256, 256, 0, stream>>>(w4a, w4aH, w4aL, 256, RW4a);
    repack_kernel<<<(RW4b + 255) / 256, 256, 0, stream>>>(w4b, w4bH, w4bL, 512, RW4b);
    repack_kernel<<<(RW5  + 255) / 256, 256, 0, stream>>>(w5a, w5aH, w5aL, 512, RW5);
    repack_kernel<<<(RW5  + 255) / 256, 256, 0, stream>>>(w5b, w5bH, w5bL, 512, RW5);

    for (int base = 0; base < 24; base += G) {
        conv1_ndhwc<<<dim3(1568, 4, G), 256, 0, stream>>>(sup, qry, base, w1, b1, AH, AL);
        conv_mfma<64, 128, 16, 56, 56, 1><<<dim3(196, 2, G), 256, 0, stream>>>(
            AH, AL, w2H, w2L, b2, BH, BL, nullptr);
        conv_mfma<128, 256, 8, 28, 28, 0><<<dim3(32, 4, G), 256, 0, stream>>>(
            BH, BL, w3aH, w3aL, b3a, AH, AL, nullptr);
        conv_mfma<256, 256, 8, 28, 28, 1><<<dim3(32, 4, G), 256, 0, stream>>>(
            AH, AL, w3bH, w3bL, b3b, BH, BL, nullptr);
        conv_mfma<256, 512, 4, 14, 14, 0><<<dim3(4, 8, G), 256, 0, stream>>>(
            BH, BL, w4aH, w4aL, b4a, AH, AL, nullptr);
        conv_mfma<512, 512, 4, 14, 14, 1><<<dim3(4, 8, G), 256, 0, stream>>>(
            AH, AL, w4bH, w4bL, b4b,
            c4H + (size_t)base * 50176, c4L + (size_t)base * 50176, nullptr);
    }

    // conv5a/5b on the MFMA path over all 24 clips
    conv_mfma<512, 512, 2, 7, 7, 0><<<dim3(1, 8, 24), 256, 0, stream>>>(
        c4H, c4L, w5aH, w5aL, b5a, c5H, c5L, nullptr);
    conv_mfma<512, 512, 2, 7, 7, 3><<<dim3(1, 8, 24), 256, 0, stream>>>(
        c5H, c5L, w5bH, w5bL, b5b, nullptr, nullptr, x5b24);

    fc_kernel<<<(4096 * 64 + 255) / 256, 256, 0, stream>>>(x5b24, w6, b6, fc6o, 8192, 4096);
    fc_kernel<<<(4096 * 64 + 255) / 256, 256, 0, stream>>>(fc6o, w7, b7, feat, 4096, 4096);
    dots_kernel<<<168, 256, 0, stream>>>(feat, dotsb);
    sinkhorn_kernel<<<1, 64, 0, stream>>>(dotsb, out);
}